// Round 2
// baseline (1051.617 us; speedup 1.0000x reference)
//
#include <hip/hip_runtime.h>

struct PackArgs {
  const float* W[6];
  const float* b[6];
};

// One block per output col (n) across all 6 layers. Packs sign bits of W rows
// into TRANSPOSED layout Bt[word * 512 + n] so the GEMM's per-word loads are
// lane-coalesced. Pad bits (k >= K) are 0 in both A and B packs.
__global__ __launch_bounds__(256) void pack_w_kernel(PackArgs a, unsigned* Bt1, unsigned* ByT, int* bs)
{
  int blk = blockIdx.x;
  int l, n;
  if      (blk < 500)  { l = 0; n = blk; }
  else if (blk < 900)  { l = 1; n = blk - 500; }
  else if (blk < 1250) { l = 2; n = blk - 900; }
  else if (blk < 1550) { l = 3; n = blk - 1250; }
  else if (blk < 1850) { l = 4; n = blk - 1550; }
  else                 { l = 5; n = blk - 1850; }
  const int Ks[6] = {4096, 500, 400, 350, 300, 300};
  int K = Ks[l];
  int chunks = (l == 0) ? 64 : 8;                      // 64-bit chunks
  unsigned* Bout = (l == 0) ? Bt1 : (ByT + (size_t)(l - 1) * 16 * 512);
  const float* Wrow = a.W[l] + (size_t)n * K;
  int lane = threadIdx.x & 63;
  int wv = threadIdx.x >> 6;
  for (int c = wv; c < chunks; c += 4) {
    int k = c * 64 + lane;
    bool pred = (k < K) && (Wrow[k] >= 0.0f);
    unsigned long long m = __ballot(pred);
    if (lane == 0) {
      Bout[(size_t)(2 * c) * 512 + n]     = (unsigned)m;
      Bout[(size_t)(2 * c + 1) * 512 + n] = (unsigned)(m >> 32);
    }
  }
  if (threadIdx.x == 0) bs[l * 512 + n] = (a.b[l][n] >= 0.0f) ? 1 : -1;
}

// Layer 1: reads x (fp32) once, ballot-packs 16 rows x 4096 sign bits into LDS
// (one barrier), then streams transposed B straight from global (L1/L2-hot,
// coalesced) through an XOR-popcount inner loop. int16 y out + exact integer
// column stats via LDS reduce + one global atomic per col per block.
__global__ __launch_bounds__(256, 4) void gemm1_kernel(const float* __restrict__ x,
    const unsigned* __restrict__ Bt, const int* __restrict__ bs1,
    short* __restrict__ y1, int* __restrict__ gs, unsigned long long* __restrict__ gq)
{
  __shared__ __align__(16) unsigned Abits[16 * 128];   // 8 KB: 16 rows x 4096 bits
  __shared__ int red_s[512];
  __shared__ int red_q[512];
  int tid = threadIdx.x;
  int lane = tid & 63, wv = tid >> 6;
  int cg = lane;           // col = jj*64 + cg
  int rg = wv;             // rows rg*4 .. rg*4+3
  int row0 = blockIdx.x * 16;

  red_s[tid] = 0; red_s[tid + 256] = 0;
  red_q[tid] = 0; red_q[tid + 256] = 0;

  // ---- stage A bits: wave wv packs rows wv*4..wv*4+3 (64 chunks each) ----
  for (int i0 = wv * 256; i0 < wv * 256 + 256; i0 += 8) {
    int r = i0 >> 6;
    int cb = i0 & 63;
    const float* xp = x + (size_t)(row0 + r) * 4096 + cb * 64 + lane;
    float v[8];
#pragma unroll
    for (int u = 0; u < 8; u++) v[u] = xp[u * 64];
#pragma unroll
    for (int u = 0; u < 8; u++) {
      unsigned long long m = __ballot(v[u] >= 0.0f);
      if (lane == 0)
        *(unsigned long long*)&Abits[r * 128 + 2 * (cb + u)] = m;
    }
  }
  __syncthreads();

  unsigned acc[4][8];
#pragma unroll
  for (int r = 0; r < 4; r++)
#pragma unroll
    for (int j = 0; j < 8; j++) acc[r][j] = 0;

  const unsigned* bp[8];
#pragma unroll
  for (int jj = 0; jj < 8; jj++) bp[jj] = Bt + jj * 64 + cg;

#pragma unroll 2
  for (int w4 = 0; w4 < 32; w4++) {
    uint4 av[4];
#pragma unroll
    for (int r = 0; r < 4; r++)
      av[r] = *(const uint4*)&Abits[(rg * 4 + r) * 128 + w4 * 4];   // wave-uniform -> broadcast
#pragma unroll
    for (int jj = 0; jj < 8; jj++) {
      unsigned b0 = bp[jj][(size_t)(w4 * 4 + 0) * 512];
      unsigned b1 = bp[jj][(size_t)(w4 * 4 + 1) * 512];
      unsigned b2 = bp[jj][(size_t)(w4 * 4 + 2) * 512];
      unsigned b3 = bp[jj][(size_t)(w4 * 4 + 3) * 512];
#pragma unroll
      for (int r = 0; r < 4; r++)
        acc[r][jj] += __popc(av[r].x ^ b0) + __popc(av[r].y ^ b1)
                    + __popc(av[r].z ^ b2) + __popc(av[r].w ^ b3);
    }
  }

  // ---- epilogue: y write + per-block exact int stats ----
#pragma unroll
  for (int jj = 0; jj < 8; jj++) {
    int col = jj * 64 + cg;
    int bsv = (col < 500) ? bs1[col] : 0;
    int s = 0, q = 0;
#pragma unroll
    for (int r = 0; r < 4; r++) {
      int y = 4096 - 2 * (int)acc[r][jj] + bsv;
      if (col < 500)
        y1[(size_t)(row0 + rg * 4 + r) * 512 + col] = (short)y;
      s += y; q += y * y;
    }
    if (col < 500) {
      atomicAdd(&red_s[col], s);
      atomicAdd(&red_q[col], q);   // per-block q <= 16*4097^2 < 2^31, fits int
    }
  }
  __syncthreads();
  for (int c = tid; c < 512; c += 256) {
    if (c < 500) {
      atomicAdd(&gs[c], red_s[c]);
      atomicAdd(&gq[c], (unsigned long long)(long long)red_q[c]);
    }
  }
}

// Layers 2..6: binarize previous y on the fly (threshold from prev-layer
// integer stats + gamma/beta), single-barrier streaming bit-GEMM, B from
// global (32 KB, L1-hot). Layer 6 writes fp32 d_out, no stats.
__global__ __launch_bounds__(256, 4) void gemmy_kernel(
    const short* __restrict__ yin, int Kin,
    const int* __restrict__ gs_in, const unsigned long long* __restrict__ gq_in,
    const float* __restrict__ g_in, const float* __restrict__ be_in,
    const unsigned* __restrict__ Bt, const int* __restrict__ bsl,
    int Nout,
    short* __restrict__ yout, int* __restrict__ gs_out, unsigned long long* __restrict__ gq_out,
    float* __restrict__ fout, int is_final)
{
  __shared__ __align__(16) unsigned Abits[16 * 16];    // 1 KB: 16 rows x 512 bits
  __shared__ float thr_t[512], thr_g[512], thr_c[512];
  __shared__ int red_s[512], red_q[512];
  int tid = threadIdx.x;
  int lane = tid & 63, wv = tid >> 6;
  int cg = lane, rg = wv;
  int row0 = blockIdx.x * 16;

  // thresholds: bit = ((y - t)*sg + c) >= 0 reproduces sign(bn(y)) exactly
  for (int k = tid; k < 512; k += 256) {
    red_s[k] = 0; red_q[k] = 0;
    float t = 0.f, sg = 0.f, cc = -1.f;
    if (k < Kin) {
      float m  = (float)gs_in[k] * (1.0f / 16384.0f);
      float ms = (float)gq_in[k] * (1.0f / 16384.0f);
      float var = fmaxf(ms - m * m, 0.0f);
      float g = g_in[k], be = be_in[k];
      if (g != 0.0f) {
        t = m - be * sqrtf(var + 1e-5f) / g;
        sg = (g > 0.0f) ? 1.0f : -1.0f;
        cc = 0.0f;
      } else { t = 0.0f; sg = 0.0f; cc = be; }
    }
    thr_t[k] = t; thr_g[k] = sg; thr_c[k] = cc;
  }
  __syncthreads();

  // stage A bits: wave wv packs rows wv*4..wv*4+3 (8 chunks each)
  for (int i0 = wv * 32; i0 < wv * 32 + 32; i0 += 4) {
    int r = i0 >> 3;
    int cb = i0 & 7;
    const short* yp = yin + (size_t)(row0 + r) * 512;
    float v[4];
#pragma unroll
    for (int u = 0; u < 4; u++) {
      int k = (cb + u) * 64 + lane;
      v[u] = (float)yp[k];        // pad cols hold poison; predicate guards k<Kin
    }
#pragma unroll
    for (int u = 0; u < 4; u++) {
      int k = (cb + u) * 64 + lane;
      bool p = (k < Kin) && (((v[u] - thr_t[k]) * thr_g[k] + thr_c[k]) >= 0.0f);
      unsigned long long m = __ballot(p);
      if (lane == 0)
        *(unsigned long long*)&Abits[r * 16 + 2 * (cb + u)] = m;
    }
  }
  __syncthreads();

  unsigned acc[4][8];
#pragma unroll
  for (int r = 0; r < 4; r++)
#pragma unroll
    for (int j = 0; j < 8; j++) acc[r][j] = 0;

  const unsigned* bp[8];
#pragma unroll
  for (int jj = 0; jj < 8; jj++) bp[jj] = Bt + jj * 64 + cg;

#pragma unroll
  for (int w4 = 0; w4 < 4; w4++) {
    uint4 av[4];
#pragma unroll
    for (int r = 0; r < 4; r++)
      av[r] = *(const uint4*)&Abits[(rg * 4 + r) * 16 + w4 * 4];
#pragma unroll
    for (int jj = 0; jj < 8; jj++) {
      unsigned b0 = bp[jj][(size_t)(w4 * 4 + 0) * 512];
      unsigned b1 = bp[jj][(size_t)(w4 * 4 + 1) * 512];
      unsigned b2 = bp[jj][(size_t)(w4 * 4 + 2) * 512];
      unsigned b3 = bp[jj][(size_t)(w4 * 4 + 3) * 512];
#pragma unroll
      for (int r = 0; r < 4; r++)
        acc[r][jj] += __popc(av[r].x ^ b0) + __popc(av[r].y ^ b1)
                    + __popc(av[r].z ^ b2) + __popc(av[r].w ^ b3);
    }
  }

  // epilogue
#pragma unroll
  for (int jj = 0; jj < 8; jj++) {
    int col = jj * 64 + cg;
    int bsv = (col < Nout) ? bsl[col] : 0;
    int s = 0, q = 0;
#pragma unroll
    for (int r = 0; r < 4; r++) {
      int y = Kin - 2 * (int)acc[r][jj] + bsv;
      if (col < Nout) {
        if (is_final) fout[(size_t)(row0 + rg * 4 + r) * Nout + col] = (float)y;
        else          yout[(size_t)(row0 + rg * 4 + r) * 512 + col] = (short)y;
      }
      s += y; q += y * y;
    }
    if (!is_final && col < Nout) {
      atomicAdd(&red_s[col], s);
      atomicAdd(&red_q[col], q);
    }
  }
  if (!is_final) {
    __syncthreads();
    for (int c = tid; c < 512; c += 256) {
      if (c < Nout) {
        atomicAdd(&gs_out[c], red_s[c]);
        atomicAdd(&gq_out[c], (unsigned long long)(long long)red_q[c]);
      }
    }
  }
}

extern "C" void kernel_launch(void* const* d_in, const int* in_sizes, int n_in,
                              void* d_out, int out_size, void* d_ws, size_t ws_size,
                              hipStream_t stream)
{
  (void)in_sizes; (void)n_in; (void)out_size; (void)ws_size;
  char* ws = (char*)d_ws;
  // workspace layout (bytes):
  //   Bt1 bits:     0      .. 262144   (128 words x 512 cols, transposed)
  //   Bt2..6 bits:  262144 .. 425984   (5 x 16 words x 512 cols)
  //   bias signs:   425984 .. 438272   (6 x 512 int)
  //   col sums:     438272 .. 448512   (5 x 512 int)
  //   col sumsq:    448512 .. 468992   (5 x 512 u64)
  //   yA, yB:       471040 ..          (2 x 16384 x 512 int16 = 33.5 MB)
  unsigned* Bt1 = (unsigned*)(ws);
  unsigned* ByT = (unsigned*)(ws + 262144);
  int* bs       = (int*)(ws + 425984);
  int* gs       = (int*)(ws + 438272);
  unsigned long long* gq = (unsigned long long*)(ws + 448512);
  short* yA = (short*)(ws + 471040);
  short* yB = yA + (size_t)16384 * 512;

  hipMemsetAsync(ws + 438272, 0, 30720, stream);  // zero all stats

  PackArgs pa;
  pa.W[0] = (const float*)d_in[1];  pa.b[0] = (const float*)d_in[2];
  pa.W[1] = (const float*)d_in[5];  pa.b[1] = (const float*)d_in[6];
  pa.W[2] = (const float*)d_in[9];  pa.b[2] = (const float*)d_in[10];
  pa.W[3] = (const float*)d_in[13]; pa.b[3] = (const float*)d_in[14];
  pa.W[4] = (const float*)d_in[17]; pa.b[4] = (const float*)d_in[18];
  pa.W[5] = (const float*)d_in[21]; pa.b[5] = (const float*)d_in[22];

  pack_w_kernel<<<1885, 256, 0, stream>>>(pa, Bt1, ByT, bs);
  gemm1_kernel<<<1024, 256, 0, stream>>>((const float*)d_in[0], Bt1, bs, yA, gs, gq);

  // layer 2: y1(K=500) -> y2(N=400)
  gemmy_kernel<<<1024, 256, 0, stream>>>(yA, 500, gs, gq,
      (const float*)d_in[3], (const float*)d_in[4],
      ByT + 0 * 16 * 512, bs + 512, 400,
      yB, gs + 512, gq + 512, nullptr, 0);
  // layer 3: y2(400) -> y3(350)
  gemmy_kernel<<<1024, 256, 0, stream>>>(yB, 400, gs + 512, gq + 512,
      (const float*)d_in[7], (const float*)d_in[8],
      ByT + 1 * 16 * 512, bs + 1024, 350,
      yA, gs + 1024, gq + 1024, nullptr, 0);
  // layer 4: y3(350) -> y4(300)
  gemmy_kernel<<<1024, 256, 0, stream>>>(yA, 350, gs + 1024, gq + 1024,
      (const float*)d_in[11], (const float*)d_in[12],
      ByT + 2 * 16 * 512, bs + 1536, 300,
      yB, gs + 1536, gq + 1536, nullptr, 0);
  // layer 5: y4(300) -> y5(300)
  gemmy_kernel<<<1024, 256, 0, stream>>>(yB, 300, gs + 1536, gq + 1536,
      (const float*)d_in[15], (const float*)d_in[16],
      ByT + 3 * 16 * 512, bs + 2048, 300,
      yA, gs + 2048, gq + 2048, nullptr, 0);
  // layer 6: y5(300) -> out(35), fp32, no stats
  gemmy_kernel<<<1024, 256, 0, stream>>>(yA, 300, gs + 2048, gq + 2048,
      (const float*)d_in[19], (const float*)d_in[20],
      ByT + 4 * 16 * 512, bs + 2560, 35,
      nullptr, nullptr, nullptr, (float*)d_out, 1);
}

// Round 4
// 875.407 us; speedup vs baseline: 1.2013x; 1.2013x over previous
//
#include <hip/hip_runtime.h>
#include <hip/hip_cooperative_groups.h>

namespace cg = cooperative_groups;

// ============================ shared arg struct ============================
struct Args {
  const float* x;
  const float* W[6];
  const float* b[6];
  const float* g[5];
  const float* be[5];
  float* out;
  unsigned* Bt1;            // [128 words][512 cols] layer-1 weight bits (transposed)
  unsigned* ByT;            // 5 x [16 words][512 cols]
  int* bs;                  // [6][512] bias signs (+1/-1)
  int* gs;                  // [5][512] col sums (int, exact)
  unsigned long long* gq;   // [5][512] col sumsq (u64, exact)
};

// ===================== PRIMARY: one cooperative kernel =====================
// 512 blocks x 256 thr, 32 rows/block resident for the whole net. Thread
// (wave wv, lane) holds y[r][jj] = row row0+wv*8+r, col jj*64+lane in regs.
// A-bits via in-wave __ballot (wave-uniform); B bits staged in 16KB LDS
// chunks ([word][col]: bank = col%32, 2-way = free). Exact-int BN stats.
__global__ __launch_bounds__(256, 2) void bnn_all(Args a)
{
  __shared__ __align__(16) unsigned Bsw[8 * 512];    // 16 KB
  __shared__ __align__(16) float thrbuf[1536];       // 6 KB; aliased by red_s/red_q
  int* red_s = (int*)thrbuf;
  int* red_q = red_s + 512;

  const int tid = threadIdx.x;
  const int lane = tid & 63;
  const int wv = tid >> 6;
  const int row0 = blockIdx.x * 32;
  cg::grid_group grid = cg::this_grid();

  // ---------- phase 0: zero stats + pack weight/bias sign bits ----------
  {
    int idx = blockIdx.x * 256 + tid;
    if (idx < 7680) ((int*)a.gs)[idx] = 0;   // gs(10240B)+gq(20480B) contiguous
  }
  for (int R = blockIdx.x; R < 1885; R += 512) {
    int l, n;
    if      (R < 500)  { l = 0; n = R; }
    else if (R < 900)  { l = 1; n = R - 500; }
    else if (R < 1250) { l = 2; n = R - 900; }
    else if (R < 1550) { l = 3; n = R - 1250; }
    else if (R < 1850) { l = 4; n = R - 1550; }
    else               { l = 5; n = R - 1850; }
    const int Ks[6] = {4096, 500, 400, 350, 300, 300};
    int K = Ks[l];
    int chunks = (l == 0) ? 64 : 8;
    unsigned* Bout = (l == 0) ? a.Bt1 : (a.ByT + (size_t)(l - 1) * 16 * 512);
    const float* Wrow = a.W[l] + (size_t)n * K;
    for (int c = wv; c < chunks; c += 4) {
      int k = c * 64 + lane;
      bool pred = (k < K) && (Wrow[k] >= 0.0f);
      unsigned long long m = __ballot(pred);
      if (lane == 0) {
        Bout[(size_t)(2 * c) * 512 + n]     = (unsigned)m;
        Bout[(size_t)(2 * c + 1) * 512 + n] = (unsigned)(m >> 32);
      }
    }
    if (tid == 0) a.bs[l * 512 + n] = (a.b[l][n] >= 0.0f) ? 1 : -1;
  }
  __threadfence();
  grid.sync();

  // ---------- layer 1: x read once -> y[8][8] registers ----------
  int y[8][8];
#pragma unroll
  for (int r = 0; r < 8; r++)
#pragma unroll
    for (int j = 0; j < 8; j++) y[r][j] = 0;

  for (int kc = 0; kc < 16; kc++) {          // 16 chunks of 256 K-bits (8 words)
    __syncthreads();                         // Bsw reuse guard
    const uint4* src = (const uint4*)(a.Bt1 + kc * 4096);
#pragma unroll
    for (int i = 0; i < 4; i++)
      ((uint4*)Bsw)[i * 256 + tid] = src[i * 256 + tid];
    unsigned Aw[8][8];
#pragma unroll
    for (int r = 0; r < 8; r++) {
      const float* xp = a.x + (size_t)(row0 + wv * 8 + r) * 4096 + kc * 256 + lane;
      float xv[4];
#pragma unroll
      for (int cb = 0; cb < 4; cb++) xv[cb] = xp[cb * 64];
#pragma unroll
      for (int cb = 0; cb < 4; cb++) {
        unsigned long long m = __ballot(xv[cb] >= 0.0f);
        Aw[r][2 * cb]     = (unsigned)m;
        Aw[r][2 * cb + 1] = (unsigned)(m >> 32);
      }
    }
    __syncthreads();
#pragma unroll
    for (int w = 0; w < 8; w++) {
#pragma unroll
      for (int jj = 0; jj < 8; jj++) {
        unsigned bw = Bsw[(w << 9) + (jj << 6) + lane];
#pragma unroll
        for (int r = 0; r < 8; r++)
          y[r][jj] += __popc(Aw[r][w] ^ bw);
      }
    }
  }
#pragma unroll
  for (int jj = 0; jj < 8; jj++) {
    int col = (jj << 6) + lane;
    int bsv = (col < 500) ? a.bs[col] : 0;
#pragma unroll
    for (int r = 0; r < 8; r++) y[r][jj] = 4096 - 2 * y[r][jj] + bsv;
  }
  // layer-1 stats (slot 0)
  {
    __syncthreads();
    red_s[tid] = 0; red_s[tid + 256] = 0;
    red_q[tid] = 0; red_q[tid + 256] = 0;
    __syncthreads();
#pragma unroll
    for (int jj = 0; jj < 8; jj++) {
      int col = (jj << 6) + lane;
      if (col < 500) {
        int s = 0, q = 0;
#pragma unroll
        for (int r = 0; r < 8; r++) { s += y[r][jj]; q += y[r][jj] * y[r][jj]; }
        atomicAdd(&red_s[col], s);
        atomicAdd(&red_q[col], q);   // per-block <= 32*4097^2 < 2^31
      }
    }
    __syncthreads();
    for (int c = tid; c < 500; c += 256) {
      atomicAdd(&a.gs[c], red_s[c]);
      atomicAdd(&a.gq[c], (unsigned long long)(long long)red_q[c]);
    }
    __threadfence();
    grid.sync();
  }

  // ---------- layers 2..6 ----------
  const int Kins[5]  = {500, 400, 350, 300, 300};
  const int Nouts[5] = {400, 350, 300, 300, 35};
#pragma unroll 1
  for (int li = 1; li <= 5; li++) {
    const int Kin  = Kins[li - 1];
    const int Nout = Nouts[li - 1];
    const bool final_layer = (li == 5);
    const int* gs_in = a.gs + (size_t)(li - 1) * 512;
    const unsigned long long* gq_in = a.gq + (size_t)(li - 1) * 512;
    const unsigned* Bl = a.ByT + (size_t)(li - 1) * 16 * 512;
    const int* bsl = a.bs + (size_t)li * 512;

    __syncthreads();   // prev epilogue LDS reads done before thrbuf rewrite
    for (int k = tid; k < 512; k += 256) {
      float t = 0.f, sg = 0.f, cc = -1.f;
      if (k < Kin) {
        float m  = (float)gs_in[k] * (1.0f / 16384.0f);
        float ms = (float)gq_in[k] * (1.0f / 16384.0f);
        float var = fmaxf(ms - m * m, 0.0f);
        float gv = a.g[li - 1][k], be = a.be[li - 1][k];
        if (gv != 0.0f) {
          t = m - be * sqrtf(var + 1e-5f) / gv;
          sg = (gv > 0.0f) ? 1.0f : -1.0f;
          cc = 0.0f;
        } else { t = 0.0f; sg = 0.0f; cc = be; }
      }
      thrbuf[k] = t; thrbuf[512 + k] = sg; thrbuf[1024 + k] = cc;
    }

    int nacc[8][8];
#pragma unroll
    for (int r = 0; r < 8; r++)
#pragma unroll
      for (int j = 0; j < 8; j++) nacc[r][j] = 0;

    for (int c2 = 0; c2 < 2; c2++) {
      __syncthreads();   // thr visible (c2=0) / Bsw reuse (c2=1)
      const uint4* src = (const uint4*)(Bl + c2 * 4096);
#pragma unroll
      for (int i = 0; i < 4; i++)
        ((uint4*)Bsw)[i * 256 + tid] = src[i * 256 + tid];
      unsigned Aw[8][8];
#pragma unroll
      for (int cb = 0; cb < 4; cb++) {
        int k = c2 * 256 + (cb << 6) + lane;
        float t = thrbuf[k], sg = thrbuf[512 + k], cc = thrbuf[1024 + k];
#pragma unroll
        for (int r = 0; r < 8; r++) {
          bool p = (k < Kin) &&
                   ((((float)y[r][c2 * 4 + cb] - t) * sg + cc) >= 0.0f);
          unsigned long long m = __ballot(p);
          Aw[r][2 * cb]     = (unsigned)m;
          Aw[r][2 * cb + 1] = (unsigned)(m >> 32);
        }
      }
      __syncthreads();
#pragma unroll
      for (int w = 0; w < 8; w++) {
#pragma unroll
        for (int jj = 0; jj < 8; jj++) {
          unsigned bw = Bsw[(w << 9) + (jj << 6) + lane];
#pragma unroll
          for (int r = 0; r < 8; r++)
            nacc[r][jj] += __popc(Aw[r][w] ^ bw);
        }
      }
    }
#pragma unroll
    for (int jj = 0; jj < 8; jj++) {
      int col = (jj << 6) + lane;
      int bsv = (col < Nout) ? bsl[col] : 0;
#pragma unroll
      for (int r = 0; r < 8; r++) {
        int v = Kin - 2 * nacc[r][jj] + bsv;
        y[r][jj] = v;
        if (final_layer && col < 35)
          a.out[(size_t)(row0 + wv * 8 + r) * 35 + col] = (float)v;
      }
    }
    if (!final_layer) {
      int* gs_out = a.gs + (size_t)li * 512;
      unsigned long long* gq_out = a.gq + (size_t)li * 512;
      __syncthreads();
      red_s[tid] = 0; red_s[tid + 256] = 0;
      red_q[tid] = 0; red_q[tid + 256] = 0;
      __syncthreads();
#pragma unroll
      for (int jj = 0; jj < 8; jj++) {
        int col = (jj << 6) + lane;
        if (col < Nout) {
          int s = 0, q = 0;
#pragma unroll
          for (int r = 0; r < 8; r++) { s += y[r][jj]; q += y[r][jj] * y[r][jj]; }
          atomicAdd(&red_s[col], s);
          atomicAdd(&red_q[col], q);
        }
      }
      __syncthreads();
      for (int c = tid; c < Nout; c += 256) {
        atomicAdd(&gs_out[c], red_s[c]);
        atomicAdd(&gq_out[c], (unsigned long long)(long long)red_q[c]);
      }
      __threadfence();
      grid.sync();
    }
  }
}

// ===================== FALLBACK: proven round-1 pipeline =====================
struct PackArgs { const float* W[6]; const float* b[6]; };

__global__ __launch_bounds__(256) void fb_pack(PackArgs a, unsigned* B1, unsigned* By, int* bs)
{
  int blk = blockIdx.x;
  int l, n;
  if      (blk < 500)  { l = 0; n = blk; }
  else if (blk < 900)  { l = 1; n = blk - 500; }
  else if (blk < 1250) { l = 2; n = blk - 900; }
  else if (blk < 1550) { l = 3; n = blk - 1250; }
  else if (blk < 1850) { l = 4; n = blk - 1550; }
  else                 { l = 5; n = blk - 1850; }
  const int Ks[6] = {4096, 500, 400, 350, 300, 300};
  int K = Ks[l];
  int KW = (l == 0) ? 128 : 16;
  unsigned* Bout = (l == 0) ? B1 : (By + (size_t)(l - 1) * 512 * 16);
  const float* Wrow = a.W[l] + (size_t)n * K;
  int lane = threadIdx.x & 63;
  int wvv = threadIdx.x >> 6;
  for (int c = wvv; c < KW / 2; c += 4) {
    int k = c * 64 + lane;
    bool pred = (k < K) && (Wrow[k] >= 0.0f);
    unsigned long long m = __ballot(pred);
    if (lane == 0) {
      Bout[(size_t)n * KW + 2 * c]     = (unsigned)m;
      Bout[(size_t)n * KW + 2 * c + 1] = (unsigned)(m >> 32);
    }
  }
  if (threadIdx.x == 0) bs[l * 512 + n] = (a.b[l][n] >= 0.0f) ? 1 : -1;
}

__global__ __launch_bounds__(256) void fb_gemm1(const float* __restrict__ x,
    const unsigned* __restrict__ B1, const int* __restrict__ bs1,
    short* __restrict__ y1, int* __restrict__ gs, unsigned long long* __restrict__ gq)
{
  __shared__ __align__(16) unsigned Abits[32 * 128];
  __shared__ __align__(16) unsigned Bsw[256 * 32];
  __shared__ int red_s[256];
  __shared__ int red_q[256];
  int tid = threadIdx.x;
  int lane = tid & 63, wvv = tid >> 6;
  int cg2 = tid & 31, rg = tid >> 5;
  int row0 = blockIdx.x * 32;

  for (int i0 = wvv * 512; i0 < wvv * 512 + 512; i0 += 8) {
    int r = i0 >> 6;
    int cb = i0 & 63;
    const float* xp = x + (size_t)(row0 + r) * 4096 + cb * 64 + lane;
    float v[8];
#pragma unroll
    for (int u = 0; u < 8; u++) v[u] = xp[u * 64];
#pragma unroll
    for (int u = 0; u < 8; u++) {
      unsigned long long m = __ballot(v[u] >= 0.0f);
      if (lane == 0)
        *(unsigned long long*)&Abits[r * 128 + 2 * (cb + u)] = m;
    }
  }

  for (int pass = 0; pass < 2; pass++) {
    int colbase = pass * 256;
    unsigned acc[4][8];
#pragma unroll
    for (int r = 0; r < 4; r++)
#pragma unroll
      for (int j = 0; j < 8; j++) acc[r][j] = 0;

    for (int kc = 0; kc < 4; kc++) {
      __syncthreads();
#pragma unroll
      for (int i = 0; i < 8; i++) {
        int q = i * 256 + tid;
        int c = q >> 3;
        int w4 = (q & 7) << 2;
        uint4 bv = *(const uint4*)(B1 + (size_t)(colbase + c) * 128 + kc * 32 + w4);
        int g = (w4 >> 2) ^ (c & 7);
        *(uint4*)&Bsw[c * 32 + 4 * g] = bv;
      }
      __syncthreads();
#pragma unroll
      for (int w4 = 0; w4 < 32; w4 += 4) {
        uint4 av[4];
#pragma unroll
        for (int r = 0; r < 4; r++)
          av[r] = *(const uint4*)&Abits[(rg * 4 + r) * 128 + kc * 32 + w4];
#pragma unroll
        for (int jj = 0; jj < 8; jj++) {
          int c = jj * 32 + cg2;
          int g = (w4 >> 2) ^ (c & 7);
          uint4 bv = *(const uint4*)&Bsw[c * 32 + 4 * g];
#pragma unroll
          for (int r = 0; r < 4; r++)
            acc[r][jj] += __popc(av[r].x ^ bv.x) + __popc(av[r].y ^ bv.y)
                        + __popc(av[r].z ^ bv.z) + __popc(av[r].w ^ bv.w);
        }
      }
    }
    red_s[tid] = 0; red_q[tid] = 0;
    __syncthreads();
#pragma unroll
    for (int jj = 0; jj < 8; jj++) {
      int col = colbase + jj * 32 + cg2;
      int bsv = (col < 500) ? bs1[col] : 0;
      int s = 0, q = 0;
#pragma unroll
      for (int r = 0; r < 4; r++) {
        int yv = 4096 - 2 * (int)acc[r][jj] + bsv;
        if (col < 500)
          y1[(size_t)(row0 + rg * 4 + r) * 500 + col] = (short)yv;
        s += yv; q += yv * yv;
      }
      atomicAdd(&red_s[jj * 32 + cg2], s);
      atomicAdd(&red_q[jj * 32 + cg2], q);
    }
    __syncthreads();
    {
      int col = colbase + tid;
      if (col < 500) {
        atomicAdd(&gs[col], red_s[tid]);
        atomicAdd(&gq[col], (unsigned long long)(long long)red_q[tid]);
      }
    }
  }
}

__global__ __launch_bounds__(256) void fb_gemmy(
    const short* __restrict__ yin, int strin, int Kin,
    const int* __restrict__ gs_in, const unsigned long long* __restrict__ gq_in,
    const float* __restrict__ g_in, const float* __restrict__ be_in,
    const unsigned* __restrict__ Bb, const int* __restrict__ bsl,
    int Nout, int strout, int passes,
    short* __restrict__ yout, int* __restrict__ gs_out, unsigned long long* __restrict__ gq_out,
    float* __restrict__ fout, int is_final)
{
  __shared__ __align__(16) unsigned Abits[32 * 16];
  __shared__ __align__(16) unsigned Bsw[256 * 16];
  __shared__ float thr_t[512], thr_g[512], thr_c[512];
  __shared__ int red_s[256], red_q[256];
  int tid = threadIdx.x;
  int lane = tid & 63, wvv = tid >> 6;
  int cg2 = tid & 31, rg = tid >> 5;
  int row0 = blockIdx.x * 32;

  for (int k = tid; k < 512; k += 256) {
    float t = 0.f, sg = 0.f, cc = -1.f;
    if (k < Kin) {
      float m  = (float)gs_in[k] * (1.0f / 16384.0f);
      float ms = (float)gq_in[k] * (1.0f / 16384.0f);
      float var = fmaxf(ms - m * m, 0.0f);
      float g = g_in[k], be = be_in[k];
      if (g != 0.0f) {
        t = m - be * sqrtf(var + 1e-5f) / g;
        sg = (g > 0.0f) ? 1.0f : -1.0f;
        cc = 0.0f;
      } else { t = 0.0f; sg = 0.0f; cc = be; }
    }
    thr_t[k] = t; thr_g[k] = sg; thr_c[k] = cc;
  }
  __syncthreads();

  for (int i0 = wvv * 64; i0 < wvv * 64 + 64; i0 += 4) {
    int r = i0 >> 3;
    int cb = i0 & 7;
    const short* yp = yin + (size_t)(row0 + r) * strin;
    float v[4];
#pragma unroll
    for (int u = 0; u < 4; u++) {
      int k = (cb + u) * 64 + lane;
      v[u] = (k < Kin) ? (float)yp[k] : -1.0f;
    }
#pragma unroll
    for (int u = 0; u < 4; u++) {
      int k = (cb + u) * 64 + lane;
      bool p = (k < Kin) && (((v[u] - thr_t[k]) * thr_g[k] + thr_c[k]) >= 0.0f);
      unsigned long long m = __ballot(p);
      if (lane == 0)
        *(unsigned long long*)&Abits[r * 16 + 2 * (cb + u)] = m;
    }
  }

  for (int pass = 0; pass < passes; pass++) {
    int colbase = pass * 256;
    __syncthreads();
#pragma unroll
    for (int i = 0; i < 4; i++) {
      int q = i * 256 + tid;
      int c = q >> 2;
      int w4 = (q & 3) << 2;
      uint4 bv = *(const uint4*)(Bb + (size_t)(colbase + c) * 16 + w4);
      int g = (w4 >> 2) ^ (c & 3);
      *(uint4*)&Bsw[c * 16 + 4 * g] = bv;
    }
    __syncthreads();
    unsigned acc[4][8];
#pragma unroll
    for (int r = 0; r < 4; r++)
#pragma unroll
      for (int j = 0; j < 8; j++) acc[r][j] = 0;
#pragma unroll
    for (int w4 = 0; w4 < 4; w4++) {
      uint4 av[4];
#pragma unroll
      for (int r = 0; r < 4; r++)
        av[r] = *(const uint4*)&Abits[(rg * 4 + r) * 16 + w4 * 4];
#pragma unroll
      for (int jj = 0; jj < 8; jj++) {
        int c = jj * 32 + cg2;
        int g = (w4) ^ (c & 3);
        uint4 bv = *(const uint4*)&Bsw[c * 16 + 4 * g];
#pragma unroll
        for (int r = 0; r < 4; r++)
          acc[r][jj] += __popc(av[r].x ^ bv.x) + __popc(av[r].y ^ bv.y)
                      + __popc(av[r].z ^ bv.z) + __popc(av[r].w ^ bv.w);
      }
    }
    red_s[tid] = 0; red_q[tid] = 0;
    __syncthreads();
#pragma unroll
    for (int jj = 0; jj < 8; jj++) {
      int col = colbase + jj * 32 + cg2;
      int bsv = (col < Nout) ? bsl[col] : 0;
      int s = 0, q = 0;
#pragma unroll
      for (int r = 0; r < 4; r++) {
        int yv = Kin - 2 * (int)acc[r][jj] + bsv;
        if (col < Nout) {
          if (is_final) fout[(size_t)(row0 + rg * 4 + r) * Nout + col] = (float)yv;
          else          yout[(size_t)(row0 + rg * 4 + r) * strout + col] = (short)yv;
        }
        s += yv; q += yv * yv;
      }
      if (!is_final && col < Nout) {
        atomicAdd(&red_s[jj * 32 + cg2], s);
        atomicAdd(&red_q[jj * 32 + cg2], q);
      }
    }
    if (!is_final) {
      __syncthreads();
      int col = colbase + tid;
      if (col < Nout) {
        atomicAdd(&gs_out[col], red_s[tid]);
        atomicAdd(&gq_out[col], (unsigned long long)(long long)red_q[tid]);
      }
      __syncthreads();
    }
  }
}

// ================================ host ================================
extern "C" void kernel_launch(void* const* d_in, const int* in_sizes, int n_in,
                              void* d_out, int out_size, void* d_ws, size_t ws_size,
                              hipStream_t stream)
{
  (void)in_sizes; (void)n_in; (void)out_size; (void)ws_size;
  char* ws = (char*)d_ws;
  unsigned* Bt1 = (unsigned*)(ws);
  unsigned* ByT = (unsigned*)(ws + 262144);
  int* bs       = (int*)(ws + 425984);
  int* gs       = (int*)(ws + 438272);
  unsigned long long* gq = (unsigned long long*)(ws + 448512);
  short* yA = (short*)(ws + 471040);
  short* yB = yA + (size_t)16384 * 512;

  Args ka;
  ka.x    = (const float*)d_in[0];
  ka.W[0] = (const float*)d_in[1];  ka.b[0] = (const float*)d_in[2];
  ka.W[1] = (const float*)d_in[5];  ka.b[1] = (const float*)d_in[6];
  ka.W[2] = (const float*)d_in[9];  ka.b[2] = (const float*)d_in[10];
  ka.W[3] = (const float*)d_in[13]; ka.b[3] = (const float*)d_in[14];
  ka.W[4] = (const float*)d_in[17]; ka.b[4] = (const float*)d_in[18];
  ka.W[5] = (const float*)d_in[21]; ka.b[5] = (const float*)d_in[22];
  ka.g[0] = (const float*)d_in[3];  ka.be[0] = (const float*)d_in[4];
  ka.g[1] = (const float*)d_in[7];  ka.be[1] = (const float*)d_in[8];
  ka.g[2] = (const float*)d_in[11]; ka.be[2] = (const float*)d_in[12];
  ka.g[3] = (const float*)d_in[15]; ka.be[3] = (const float*)d_in[16];
  ka.g[4] = (const float*)d_in[19]; ka.be[4] = (const float*)d_in[20];
  ka.out = (float*)d_out;
  ka.Bt1 = Bt1; ka.ByT = ByT; ka.bs = bs; ka.gs = gs; ka.gq = gq;

  // Env-constant gate: can 512 blocks (2/CU on 256 CUs) be co-resident?
  int maxPerCU = 0;
  hipError_t qerr = hipOccupancyMaxActiveBlocksPerMultiprocessor(
      &maxPerCU, reinterpret_cast<const void*>(&bnn_all), 256, 0);
  bool use_coop = (qerr == hipSuccess) && (maxPerCU >= 2);

  if (use_coop) {
    void* args_arr[] = { &ka };
    hipLaunchCooperativeKernel(reinterpret_cast<void*>(&bnn_all),
                               dim3(512), dim3(256), args_arr, 0, stream);
    return;
  }

  // -------- fallback: proven multi-kernel pipeline (round-1 structure) --------
  hipMemsetAsync(ws + 438272, 0, 30720, stream);  // zero stats

  PackArgs pa;
  for (int i = 0; i < 6; i++) { pa.W[i] = ka.W[i]; pa.b[i] = ka.b[i]; }

  fb_pack<<<1885, 256, 0, stream>>>(pa, Bt1, ByT, bs);
  fb_gemm1<<<512, 256, 0, stream>>>((const float*)d_in[0], Bt1, bs, yA, gs, gq);
  fb_gemmy<<<512, 256, 0, stream>>>(yA, 500, 500, gs, gq,
      ka.g[0], ka.be[0], ByT + 0 * 512 * 16, bs + 512, 400, 400, 2,
      yB, gs + 512, gq + 512, nullptr, 0);
  fb_gemmy<<<512, 256, 0, stream>>>(yB, 400, 400, gs + 512, gq + 512,
      ka.g[1], ka.be[1], ByT + 1 * 512 * 16, bs + 1024, 350, 352, 2,
      yA, gs + 1024, gq + 1024, nullptr, 0);
  fb_gemmy<<<512, 256, 0, stream>>>(yA, 352, 350, gs + 1024, gq + 1024,
      ka.g[2], ka.be[2], ByT + 2 * 512 * 16, bs + 1536, 300, 300, 2,
      yB, gs + 1536, gq + 1536, nullptr, 0);
  fb_gemmy<<<512, 256, 0, stream>>>(yB, 300, 300, gs + 1536, gq + 1536,
      ka.g[3], ka.be[3], ByT + 3 * 512 * 16, bs + 2048, 300, 300, 2,
      yA, gs + 2048, gq + 2048, nullptr, 0);
  fb_gemmy<<<512, 256, 0, stream>>>(yA, 300, 300, gs + 2048, gq + 2048,
      ka.g[4], ka.be[4], ByT + 4 * 512 * 16, bs + 2560, 35, 35, 1,
      nullptr, nullptr, nullptr, (float*)d_out, 1);
}